// Round 2
// baseline (291.381 us; speedup 1.0000x reference)
//
#include <hip/hip_runtime.h>

// Deformable conv, B=16 C=64 H=W=64, COUT=128, K=3, stride=1, pad=1, dil=1.
// Plan: (1) transpose x NCHW->NHWC into ws (channel-contiguous bilinear reads)
//       (2) transpose weight -> wt[kk][oc][c]
//       (3) fused kernel: block = (b, ho) row; per kk stage weights + deformable
//           im2col into LDS, then register-blocked fp32 GEMM (4px x 8oc / thread).

__global__ __launch_bounds__(256) void transpose_x_kernel(const float* __restrict__ x,
                                                          float* __restrict__ xt) {
    __shared__ float tile[64][65];
    int bid = blockIdx.x;            // b*64 + y
    int t = threadIdx.x;
    // x[b][c][y][w] = x[((b*64 + c)*64 + y)*64 + w]
    int b = bid >> 6, y = bid & 63;
    const float* xb = x + (size_t)b * 262144 + (size_t)y * 64;  // x[b][0][y][0]
#pragma unroll
    for (int it = 0; it < 16; ++it) {            // 16*256 = 4096 = 64c * 64w
        int idx = t + it * 256;
        int c = idx >> 6, w = idx & 63;
        tile[c][w] = xb[(size_t)c * 4096 + w];
    }
    __syncthreads();
    // xt[b][y][w][c] = xt[bid*4096 + w*64 + c]
    float* dst = xt + (size_t)bid * 4096;
#pragma unroll
    for (int it = 0; it < 16; ++it) {
        int idx = t + it * 256;
        int w = idx >> 6, c = idx & 63;
        dst[idx] = tile[c][w];
    }
}

__global__ __launch_bounds__(256) void transpose_w_kernel(const float* __restrict__ wgt,
                                                          float* __restrict__ wt) {
    // wt[kk][oc][c] = weight[oc][c][kk];  total 9*128*64 = 73728
    int idx = blockIdx.x * 256 + threadIdx.x;
    int kk = idx >> 13;          // / 8192
    int r = idx & 8191;
    int oc = r >> 6, c = r & 63;
    wt[idx] = wgt[((size_t)oc * 64 + c) * 9 + kk];
}

__global__ __launch_bounds__(256) void deform_main(const float* __restrict__ xt,
                                                   const float* __restrict__ offset,
                                                   const float* __restrict__ wt,
                                                   float* __restrict__ out) {
    __shared__ float off_s[18][64];
    __shared__ float col_s[64][68];   // [wo][c], stride 68 floats (16B aligned, bank-spread)
    __shared__ float w_s[128][68];    // [oc][c]

    int bid = blockIdx.x;             // b*64 + ho
    int b = bid >> 6, ho = bid & 63;
    int t = threadIdx.x;

    // stage this row's offsets: offset[b][ch][ho][wo], ch = 2*kk + {0:y,1:x}
    {
        const float* ob = offset + (size_t)b * 18 * 4096 + ho * 64;
        for (int idx = t; idx < 18 * 64; idx += 256) {
            int ch = idx >> 6, wo = idx & 63;
            off_s[ch][wo] = ob[(size_t)ch * 4096 + wo];
        }
    }
    __syncthreads();

    float acc[4][8];
#pragma unroll
    for (int i = 0; i < 4; ++i)
#pragma unroll
        for (int j = 0; j < 8; ++j) acc[i][j] = 0.f;

    const int wo_s = t >> 2, cq = t & 3;   // sampling: thread -> (wo, 16-channel quad)
    const int px_l = t & 15, oc_l = t >> 4; // gemm: px = px_l+16i, oc = oc_l+16j
    const float* xb = xt + (size_t)b * 262144;  // xt[b][y][x][c]

    for (int kk = 0; kk < 9; ++kk) {
        // ---- stage weight slice w_s[oc][c] = wt[kk][oc][c] (coalesced) ----
        {
            const float* wk = wt + kk * 8192;
#pragma unroll
            for (int r = 0; r < 32; ++r) {
                int idx = t + r * 256;
                w_s[idx >> 6][idx & 63] = wk[idx];
            }
        }
        // ---- deformable bilinear im2col into col_s[wo][c] ----
        {
            int ky = kk / 3, kx = kk - ky * 3;
            float py = off_s[2 * kk][wo_s] + (float)(ho - 1 + ky);
            float px = off_s[2 * kk + 1][wo_s] + (float)(wo_s - 1 + kx);
            float y0f = floorf(py), x0f = floorf(px);
            float ly = py - y0f, lx = px - x0f;
            int y0 = (int)y0f, x0 = (int)x0f;
            int y1 = y0 + 1, x1 = x0 + 1;
            float w00 = (1.f - ly) * (1.f - lx), w01 = (1.f - ly) * lx;
            float w10 = ly * (1.f - lx), w11 = ly * lx;
            // per-corner validity (zero padding outside), matching reference
            bool vy0 = (y0 >= 0) & (y0 < 64), vy1 = (y1 >= 0) & (y1 < 64);
            bool vx0 = (x0 >= 0) & (x0 < 64), vx1 = (x1 >= 0) & (x1 < 64);
            if (!(vy0 & vx0)) w00 = 0.f;
            if (!(vy0 & vx1)) w01 = 0.f;
            if (!(vy1 & vx0)) w10 = 0.f;
            if (!(vy1 & vx1)) w11 = 0.f;
            int y0c = min(max(y0, 0), 63), y1c = min(max(y1, 0), 63);
            int x0c = min(max(x0, 0), 63), x1c = min(max(x1, 0), 63);
            const float* p00 = xb + ((y0c * 64 + x0c) * 64) + cq * 16;
            const float* p01 = xb + ((y0c * 64 + x1c) * 64) + cq * 16;
            const float* p10 = xb + ((y1c * 64 + x0c) * 64) + cq * 16;
            const float* p11 = xb + ((y1c * 64 + x1c) * 64) + cq * 16;
            float* cs = &col_s[wo_s][cq * 16];
#pragma unroll
            for (int q = 0; q < 4; ++q) {
                float4 a = *(const float4*)(p00 + q * 4);
                float4 bb = *(const float4*)(p01 + q * 4);
                float4 cc = *(const float4*)(p10 + q * 4);
                float4 dd = *(const float4*)(p11 + q * 4);
                float4 r;
                r.x = w00 * a.x + w01 * bb.x + w10 * cc.x + w11 * dd.x;
                r.y = w00 * a.y + w01 * bb.y + w10 * cc.y + w11 * dd.y;
                r.z = w00 * a.z + w01 * bb.z + w10 * cc.z + w11 * dd.z;
                r.w = w00 * a.w + w01 * bb.w + w10 * cc.w + w11 * dd.w;
                *(float4*)(cs + q * 4) = r;
            }
        }
        __syncthreads();
        // ---- fp32 register-blocked GEMM: acc[i][j] += col[px][c] * w[oc][c] ----
#pragma unroll
        for (int c0 = 0; c0 < 64; c0 += 4) {
            float4 cv[4];
#pragma unroll
            for (int i = 0; i < 4; ++i) cv[i] = *(const float4*)&col_s[px_l + 16 * i][c0];
            float4 wv[8];
#pragma unroll
            for (int j = 0; j < 8; ++j) wv[j] = *(const float4*)&w_s[oc_l + 16 * j][c0];
#pragma unroll
            for (int i = 0; i < 4; ++i)
#pragma unroll
                for (int j = 0; j < 8; ++j) {
                    acc[i][j] += cv[i].x * wv[j].x;
                    acc[i][j] += cv[i].y * wv[j].y;
                    acc[i][j] += cv[i].z * wv[j].z;
                    acc[i][j] += cv[i].w * wv[j].w;
                }
        }
        __syncthreads();
    }

    // ---- epilogue: out[b][oc][ho][wo], 16 consecutive px per lane group ----
    float* ob = out + (size_t)b * 128 * 4096 + ho * 64;
#pragma unroll
    for (int j = 0; j < 8; ++j)
#pragma unroll
        for (int i = 0; i < 4; ++i)
            ob[(size_t)(oc_l + 16 * j) * 4096 + px_l + 16 * i] = acc[i][j];
}

extern "C" void kernel_launch(void* const* d_in, const int* in_sizes, int n_in,
                              void* d_out, int out_size, void* d_ws, size_t ws_size,
                              hipStream_t stream) {
    const float* x = (const float*)d_in[0];
    const float* offset = (const float*)d_in[1];
    const float* wgt = (const float*)d_in[2];
    float* out = (float*)d_out;
    float* xt = (float*)d_ws;                       // 16*64*64*64 f32 = 16.78 MB
    float* wt = xt + (size_t)16 * 64 * 64 * 64;     // 9*128*64 f32   = 0.29 MB

    hipLaunchKernelGGL(transpose_x_kernel, dim3(1024), dim3(256), 0, stream, x, xt);
    hipLaunchKernelGGL(transpose_w_kernel, dim3(288), dim3(256), 0, stream, wgt, wt);
    hipLaunchKernelGGL(deform_main, dim3(1024), dim3(256), 0, stream, xt, offset, wt, out);
}

// Round 3
// 148.543 us; speedup vs baseline: 1.9616x; 1.9616x over previous
//
#include <hip/hip_runtime.h>

// Deformable conv, B=16 C=64 H=W=64, COUT=128, K=3 s=1 p=1 d=1.
// R3: bf16 MFMA GEMM. xt = NHWC f32 (bilinear stays fp32). Weights packed to
// B-fragment layout (bf16) -> waves load B global->reg. Bilinear writes col in
// A-fragment layout to LDS (lane-linear, conflict-free ds_read_b128).
// mfma_f32_16x16x32_bf16, fp32 accum. Epilogue: LDS transpose per C-tile
// (stride 68 f32) -> coalesced dwordx4 stores.

typedef short bf8 __attribute__((ext_vector_type(8)));   // 8 bf16 (4 VGPR)
typedef float f32x4 __attribute__((ext_vector_type(4)));

__device__ inline short f2bf(float f) {                  // RNE f32 -> bf16
    unsigned u = __float_as_uint(f);
    unsigned r = (u + 0x7FFFu + ((u >> 16) & 1u)) >> 16;
    return (short)r;
}

__global__ __launch_bounds__(256) void transpose_x_kernel(const float* __restrict__ x,
                                                          float* __restrict__ xt) {
    __shared__ float tile[64][65];
    int bid = blockIdx.x;            // b*64 + y
    int t = threadIdx.x;
    int b = bid >> 6, y = bid & 63;
    const float* xb = x + (size_t)b * 262144 + (size_t)y * 64;  // x[b][0][y][0]
#pragma unroll
    for (int it = 0; it < 16; ++it) {            // 16*256 = 4096 = 64c*64w
        int idx = t + it * 256;
        int c = idx >> 6, w = idx & 63;
        tile[c][w] = xb[(size_t)c * 4096 + w];
    }
    __syncthreads();
    float* dst = xt + (size_t)bid * 4096;        // xt[b][y][w][c]
#pragma unroll
    for (int it = 0; it < 16; ++it) {
        int idx = t + it * 256;
        tile[0][0] += 0.f;                       // no-op
        dst[idx] = tile[idx & 63][idx >> 6];     // [c][w] -> [w][c]
    }
}

// wf[kk][octile(8)][kstep(2)][lane(64)][i(8)] = bf16(weight[oc][c][kk])
//   oc = octile*16 + (lane&15); c = kstep*32 + (lane>>4)*8 + i
__global__ __launch_bounds__(256) void build_wfrag(const float* __restrict__ wgt,
                                                   short* __restrict__ wf) {
    int idx = blockIdx.x * 256 + threadIdx.x;    // 73728 total
    int i = idx & 7;
    int lane = (idx >> 3) & 63;
    int ks = (idx >> 9) & 1;
    int oct = (idx >> 10) & 7;
    int kk = idx >> 13;
    int oc = oct * 16 + (lane & 15);
    int c = ks * 32 + (lane >> 4) * 8 + i;
    wf[idx] = f2bf(wgt[((size_t)oc * 64 + c) * 9 + kk]);
}

__global__ __launch_bounds__(256) void deform_main(const float* __restrict__ xt,
                                                   const float* __restrict__ offset,
                                                   const short* __restrict__ wf,
                                                   float* __restrict__ out) {
    // colf: 4 pxtile * 2 kstep * 64 lane * 16B = 8192 B (A-fragment order)
    // off_s: 18*64 f32 = 4608 B at +8192
    // epilogue reuses smem: per-wave f32[16][68] = 4352 B at wave*4352
    __shared__ __align__(16) char smem[17408];
    short* colf = (short*)smem;
    float* off_s = (float*)(smem + 8192);

    int bid = blockIdx.x;             // b*64 + ho
    int b = bid >> 6, ho = bid & 63;
    int t = threadIdx.x;
    int wave = t >> 6, lane = t & 63;

    {   // stage offsets: offset[b][ch][ho][wo], ch = 2*kk + {0:y,1:x}
        const float* ob = offset + (size_t)b * 18 * 4096 + ho * 64;
        for (int idx = t; idx < 18 * 64; idx += 256)
            off_s[idx] = ob[(idx >> 6) * 4096 + (idx & 63)];
    }
    __syncthreads();

    f32x4 acc[4][2];
#pragma unroll
    for (int m = 0; m < 4; ++m)
#pragma unroll
        for (int j = 0; j < 2; ++j) acc[m][j] = (f32x4)0.f;

    // producer mapping: px = t>>2 (wo), cq = t&3 (16-channel quad)
    const int px = t >> 2, cq = t & 3;
    const int pxt = px >> 4, wo15 = px & 15, ks_p = cq >> 1, kgb = (cq & 1) * 2;
    const float* xb = xt + (size_t)b * 262144;   // xt[b][y][x][c]

    for (int kk = 0; kk < 9; ++kk) {
        // ---- B-fragments: global -> reg (L2-resident, lane-linear) ----
        bf8 bfr0[2], bfr1[2];  // [kstep] for octile 2*wave, 2*wave+1
#pragma unroll
        for (int ksi = 0; ksi < 2; ++ksi) {
            bfr0[ksi] = *(const bf8*)(wf + ((((kk * 8 + 2 * wave) * 2) + ksi) * 64 + lane) * 8);
            bfr1[ksi] = *(const bf8*)(wf + ((((kk * 8 + 2 * wave + 1) * 2) + ksi) * 64 + lane) * 8);
        }

        // ---- deformable bilinear -> colf (A-fragment layout) ----
        {
            int ky = kk / 3, kx = kk - ky * 3;
            float py = off_s[(2 * kk) * 64 + px] + (float)(ho - 1 + ky);
            float sx = off_s[(2 * kk + 1) * 64 + px] + (float)(px - 1 + kx);
            float y0f = floorf(py), x0f = floorf(sx);
            float ly = py - y0f, lx = sx - x0f;
            int y0 = (int)y0f, x0 = (int)x0f;
            int y1 = y0 + 1, x1 = x0 + 1;
            float w00 = (1.f - ly) * (1.f - lx), w01 = (1.f - ly) * lx;
            float w10 = ly * (1.f - lx), w11 = ly * lx;
            bool vy0 = (y0 >= 0) & (y0 < 64), vy1 = (y1 >= 0) & (y1 < 64);
            bool vx0 = (x0 >= 0) & (x0 < 64), vx1 = (x1 >= 0) & (x1 < 64);
            if (!(vy0 & vx0)) w00 = 0.f;
            if (!(vy0 & vx1)) w01 = 0.f;
            if (!(vy1 & vx0)) w10 = 0.f;
            if (!(vy1 & vx1)) w11 = 0.f;
            int y0c = min(max(y0, 0), 63), y1c = min(max(y1, 0), 63);
            int x0c = min(max(x0, 0), 63), x1c = min(max(x1, 0), 63);
            const float* p00 = xb + ((y0c * 64 + x0c) * 64) + cq * 16;
            const float* p01 = xb + ((y0c * 64 + x1c) * 64) + cq * 16;
            const float* p10 = xb + ((y1c * 64 + x0c) * 64) + cq * 16;
            const float* p11 = xb + ((y1c * 64 + x1c) * 64) + cq * 16;
            float r[16];
#pragma unroll
            for (int q = 0; q < 4; ++q) {
                float4 a = *(const float4*)(p00 + q * 4);
                float4 bb = *(const float4*)(p01 + q * 4);
                float4 cc = *(const float4*)(p10 + q * 4);
                float4 dd = *(const float4*)(p11 + q * 4);
                r[q * 4 + 0] = w00 * a.x + w01 * bb.x + w10 * cc.x + w11 * dd.x;
                r[q * 4 + 1] = w00 * a.y + w01 * bb.y + w10 * cc.y + w11 * dd.y;
                r[q * 4 + 2] = w00 * a.z + w01 * bb.z + w10 * cc.z + w11 * dd.z;
                r[q * 4 + 3] = w00 * a.w + w01 * bb.w + w10 * cc.w + w11 * dd.w;
            }
            // two 16B chunks: kgroup = kgb+g, lane' = (kgroup<<4)|wo15
#pragma unroll
            for (int g = 0; g < 2; ++g) {
                bf8 v;
#pragma unroll
                for (int i = 0; i < 8; ++i) v[i] = f2bf(r[g * 8 + i]);
                int lanew = ((kgb + g) << 4) | wo15;
                *(bf8*)(colf + ((pxt * 2 + ks_p) * 64 + lanew) * 8) = v;
            }
        }
        __syncthreads();

        // ---- MFMA: wave owns 64px x 32oc (octiles 2w, 2w+1) ----
#pragma unroll
        for (int ksi = 0; ksi < 2; ++ksi) {
            bf8 a[4];
#pragma unroll
            for (int m = 0; m < 4; ++m)
                a[m] = *(const bf8*)(colf + ((m * 2 + ksi) * 64 + lane) * 8);
#pragma unroll
            for (int m = 0; m < 4; ++m) {
                acc[m][0] = __builtin_amdgcn_mfma_f32_16x16x32_bf16(a[m], bfr0[ksi], acc[m][0], 0, 0, 0);
                acc[m][1] = __builtin_amdgcn_mfma_f32_16x16x32_bf16(a[m], bfr1[ksi], acc[m][1], 0, 0, 0);
            }
        }
        __syncthreads();
    }

    // ---- epilogue: C/D layout col=lane&15 (oc), row=(lane>>4)*4+r (px).
    //      LDS transpose per octile -> coalesced stores. ----
    float* ep = (float*)(smem + wave * 4352);    // f32[16][68]
    float* outb = out + (size_t)b * 128 * 4096 + ho * 64;
    const int ocl = lane & 15, hi = lane >> 4;
    const int ocr = lane >> 2, px0 = (lane & 3) * 16;
#pragma unroll
    for (int j = 0; j < 2; ++j) {
#pragma unroll
        for (int m = 0; m < 4; ++m)
            *(f32x4*)(ep + ocl * 68 + m * 16 + hi * 4) = acc[m][j];
        int ocg = (2 * wave + j) * 16 + ocr;
#pragma unroll
        for (int q = 0; q < 4; ++q) {
            f32x4 v = *(const f32x4*)(ep + ocr * 68 + px0 + q * 4);
            *(f32x4*)(outb + (size_t)ocg * 4096 + px0 + q * 4) = v;
        }
    }
}

extern "C" void kernel_launch(void* const* d_in, const int* in_sizes, int n_in,
                              void* d_out, int out_size, void* d_ws, size_t ws_size,
                              hipStream_t stream) {
    const float* x = (const float*)d_in[0];
    const float* offset = (const float*)d_in[1];
    const float* wgt = (const float*)d_in[2];
    float* out = (float*)d_out;
    float* xt = (float*)d_ws;                         // 16.78 MB f32 NHWC
    short* wfrag = (short*)(xt + (size_t)16 * 64 * 64 * 64);  // 73728 bf16

    hipLaunchKernelGGL(transpose_x_kernel, dim3(1024), dim3(256), 0, stream, x, xt);
    hipLaunchKernelGGL(build_wfrag, dim3(288), dim3(256), 0, stream, wgt, wfrag);
    hipLaunchKernelGGL(deform_main, dim3(1024), dim3(256), 0, stream, xt, offset, wfrag, out);
}

// Round 4
// 114.238 us; speedup vs baseline: 2.5507x; 1.3003x over previous
//
#include <hip/hip_runtime.h>

// Deformable conv, B=16 C=64 H=W=64, COUT=128, K=3 s=1 p=1 d=1.
// R4: (a) XCD-aware block swizzle in deform_main (per-XCD L2 working set ->
//     2 images), (b) xt stored as bf16 NHWC (halves gather footprint; bilinear
//     in fp32 on bf16 corners). GEMM unchanged: mfma_f32_16x16x32_bf16,
//     B-fragments global->reg, A-fragments via LDS, fp32 accum, LDS-transpose
//     epilogue with coalesced dwordx4 stores.

typedef short bf8 __attribute__((ext_vector_type(8)));   // 8 bf16 (4 VGPR)
typedef float f32x4 __attribute__((ext_vector_type(4)));
typedef unsigned short u16;
typedef u16 u16x8 __attribute__((ext_vector_type(8)));

__device__ inline u16 f2bf(float f) {                    // RNE f32 -> bf16
    unsigned u = __float_as_uint(f);
    return (u16)((u + 0x7FFFu + ((u >> 16) & 1u)) >> 16);
}
__device__ inline float bf2f(u16 v) {
    return __uint_as_float(((unsigned)v) << 16);
}

__global__ __launch_bounds__(256) void transpose_x_kernel(const float* __restrict__ x,
                                                          u16* __restrict__ xtb) {
    __shared__ float tile[64][65];
    int bid = blockIdx.x;            // b*64 + y
    int t = threadIdx.x;
    int b = bid >> 6, y = bid & 63;
    const float* xb = x + (size_t)b * 262144 + (size_t)y * 64;  // x[b][0][y][0]
#pragma unroll
    for (int it = 0; it < 16; ++it) {            // 16*256 = 4096 = 64c*64w
        int idx = t + it * 256;
        int c = idx >> 6, w = idx & 63;
        tile[c][w] = xb[(size_t)c * 4096 + w];
    }
    __syncthreads();
    u16* dst = xtb + (size_t)bid * 4096;         // xtb[b][y][w][c] bf16
#pragma unroll
    for (int it = 0; it < 16; ++it) {
        int idx = t + it * 256;
        dst[idx] = f2bf(tile[idx & 63][idx >> 6]);   // [c][w] -> [w][c]
    }
}

// wf[kk][octile(8)][kstep(2)][lane(64)][i(8)] = bf16(weight[oc][c][kk])
//   oc = octile*16 + (lane&15); c = kstep*32 + (lane>>4)*8 + i
__global__ __launch_bounds__(256) void build_wfrag(const float* __restrict__ wgt,
                                                   short* __restrict__ wf) {
    int idx = blockIdx.x * 256 + threadIdx.x;    // 73728 total
    int i = idx & 7;
    int lane = (idx >> 3) & 63;
    int ks = (idx >> 9) & 1;
    int oct = (idx >> 10) & 7;
    int kk = idx >> 13;
    int oc = oct * 16 + (lane & 15);
    int c = ks * 32 + (lane >> 4) * 8 + i;
    wf[idx] = (short)f2bf(wgt[((size_t)oc * 64 + c) * 9 + kk]);
}

__global__ __launch_bounds__(256) void deform_main(const u16* __restrict__ xtb,
                                                   const float* __restrict__ offset,
                                                   const short* __restrict__ wf,
                                                   float* __restrict__ out) {
    // colf: 4 pxtile * 2 kstep * 64 lane * 16B = 8192 B (A-fragment order)
    // off_s: 18*64 f32 = 4608 B at +8192
    // epilogue reuses smem: per-wave f32[16][68] = 4352 B at wave*4352
    __shared__ __align__(16) char smem[17408];
    short* colf = (short*)smem;
    float* off_s = (float*)(smem + 8192);

    // XCD-aware swizzle: nwg=1024, 8 XCDs -> XCD k owns wgid in [128k,128k+128)
    // = batch images {2k, 2k+1}: per-XCD L2 working set ~1MB of xtb.
    int wg = blockIdx.x;
    int wgid = (wg & 7) * 128 + (wg >> 3);
    int b = wgid >> 6, ho = wgid & 63;
    int t = threadIdx.x;
    int wave = t >> 6, lane = t & 63;

    {   // stage offsets: offset[b][ch][ho][wo], ch = 2*kk + {0:y,1:x}
        const float* ob = offset + (size_t)b * 18 * 4096 + ho * 64;
        for (int idx = t; idx < 18 * 64; idx += 256)
            off_s[idx] = ob[(idx >> 6) * 4096 + (idx & 63)];
    }
    __syncthreads();

    f32x4 acc[4][2];
#pragma unroll
    for (int m = 0; m < 4; ++m)
#pragma unroll
        for (int j = 0; j < 2; ++j) acc[m][j] = (f32x4)0.f;

    // producer mapping: px = t>>2 (wo), cq = t&3 (16-channel quad)
    const int px = t >> 2, cq = t & 3;
    const int pxt = px >> 4, wo15 = px & 15, ks_p = cq >> 1, kgb = (cq & 1) * 2;
    const u16* xb = xtb + (size_t)b * 262144;    // xtb[b][y][x][c] bf16

    for (int kk = 0; kk < 9; ++kk) {
        // ---- B-fragments: global -> reg (L2-resident, lane-linear) ----
        bf8 bfr0[2], bfr1[2];  // [kstep] for octile 2*wave, 2*wave+1
#pragma unroll
        for (int ksi = 0; ksi < 2; ++ksi) {
            bfr0[ksi] = *(const bf8*)(wf + ((((kk * 8 + 2 * wave) * 2) + ksi) * 64 + lane) * 8);
            bfr1[ksi] = *(const bf8*)(wf + ((((kk * 8 + 2 * wave + 1) * 2) + ksi) * 64 + lane) * 8);
        }

        // ---- deformable bilinear (fp32 on bf16 corners) -> colf ----
        {
            int ky = kk / 3, kx = kk - ky * 3;
            float py = off_s[(2 * kk) * 64 + px] + (float)(ho - 1 + ky);
            float sx = off_s[(2 * kk + 1) * 64 + px] + (float)(px - 1 + kx);
            float y0f = floorf(py), x0f = floorf(sx);
            float ly = py - y0f, lx = sx - x0f;
            int y0 = (int)y0f, x0 = (int)x0f;
            int y1 = y0 + 1, x1 = x0 + 1;
            float w00 = (1.f - ly) * (1.f - lx), w01 = (1.f - ly) * lx;
            float w10 = ly * (1.f - lx), w11 = ly * lx;
            bool vy0 = (y0 >= 0) & (y0 < 64), vy1 = (y1 >= 0) & (y1 < 64);
            bool vx0 = (x0 >= 0) & (x0 < 64), vx1 = (x1 >= 0) & (x1 < 64);
            if (!(vy0 & vx0)) w00 = 0.f;
            if (!(vy0 & vx1)) w01 = 0.f;
            if (!(vy1 & vx0)) w10 = 0.f;
            if (!(vy1 & vx1)) w11 = 0.f;
            int y0c = min(max(y0, 0), 63), y1c = min(max(y1, 0), 63);
            int x0c = min(max(x0, 0), 63), x1c = min(max(x1, 0), 63);
            const u16x8* q00 = (const u16x8*)(xb + ((y0c * 64 + x0c) * 64) + cq * 16);
            const u16x8* q01 = (const u16x8*)(xb + ((y0c * 64 + x1c) * 64) + cq * 16);
            const u16x8* q10 = (const u16x8*)(xb + ((y1c * 64 + x0c) * 64) + cq * 16);
            const u16x8* q11 = (const u16x8*)(xb + ((y1c * 64 + x1c) * 64) + cq * 16);
            // two 16B chunks: kgroup = kgb+g, lane' = (kgroup<<4)|wo15
#pragma unroll
            for (int g = 0; g < 2; ++g) {
                u16x8 a = q00[g], bb = q01[g], cc = q10[g], dd = q11[g];
                bf8 v;
#pragma unroll
                for (int i = 0; i < 8; ++i) {
                    float r = w00 * bf2f(a[i]) + w01 * bf2f(bb[i]) +
                              w10 * bf2f(cc[i]) + w11 * bf2f(dd[i]);
                    v[i] = (short)f2bf(r);
                }
                int lanew = ((kgb + g) << 4) | wo15;
                *(bf8*)(colf + ((pxt * 2 + ks_p) * 64 + lanew) * 8) = v;
            }
        }
        __syncthreads();

        // ---- MFMA: wave owns 64px x 32oc (octiles 2w, 2w+1) ----
#pragma unroll
        for (int ksi = 0; ksi < 2; ++ksi) {
            bf8 a[4];
#pragma unroll
            for (int m = 0; m < 4; ++m)
                a[m] = *(const bf8*)(colf + ((m * 2 + ksi) * 64 + lane) * 8);
#pragma unroll
            for (int m = 0; m < 4; ++m) {
                acc[m][0] = __builtin_amdgcn_mfma_f32_16x16x32_bf16(a[m], bfr0[ksi], acc[m][0], 0, 0, 0);
                acc[m][1] = __builtin_amdgcn_mfma_f32_16x16x32_bf16(a[m], bfr1[ksi], acc[m][1], 0, 0, 0);
            }
        }
        __syncthreads();
    }

    // ---- epilogue: C/D layout col=lane&15 (oc), row=(lane>>4)*4+r (px).
    //      LDS transpose per octile -> coalesced stores. ----
    float* ep = (float*)(smem + wave * 4352);    // f32[16][68]
    float* outb = out + (size_t)b * 128 * 4096 + ho * 64;
    const int ocl = lane & 15, hi = lane >> 4;
    const int ocr = lane >> 2, px0 = (lane & 3) * 16;
#pragma unroll
    for (int j = 0; j < 2; ++j) {
#pragma unroll
        for (int m = 0; m < 4; ++m)
            *(f32x4*)(ep + ocl * 68 + m * 16 + hi * 4) = acc[m][j];
        int ocg = (2 * wave + j) * 16 + ocr;
#pragma unroll
        for (int q = 0; q < 4; ++q) {
            f32x4 v = *(const f32x4*)(ep + ocr * 68 + px0 + q * 4);
            *(f32x4*)(outb + (size_t)ocg * 4096 + px0 + q * 4) = v;
        }
    }
}

extern "C" void kernel_launch(void* const* d_in, const int* in_sizes, int n_in,
                              void* d_out, int out_size, void* d_ws, size_t ws_size,
                              hipStream_t stream) {
    const float* x = (const float*)d_in[0];
    const float* offset = (const float*)d_in[1];
    const float* wgt = (const float*)d_in[2];
    float* out = (float*)d_out;
    u16* xtb = (u16*)d_ws;                              // 8.39 MB bf16 NHWC
    short* wfrag = (short*)(xtb + (size_t)16 * 64 * 64 * 64);  // 73728 bf16

    hipLaunchKernelGGL(transpose_x_kernel, dim3(1024), dim3(256), 0, stream, x, xtb);
    hipLaunchKernelGGL(build_wfrag, dim3(288), dim3(256), 0, stream, wgt, wfrag);
    hipLaunchKernelGGL(deform_main, dim3(1024), dim3(256), 0, stream, xtb, offset, wfrag, out);
}